// Round 2
// baseline (518.932 us; speedup 1.0000x reference)
//
#include <hip/hip_runtime.h>
#include <hip/hip_bf16.h>

#define BB 64
#define SS 8192
#define DD 128

typedef __attribute__((ext_vector_type(8))) short bf16x8;
typedef __attribute__((ext_vector_type(4))) float f32x4;

__device__ __forceinline__ short f2bf(float f) {
    unsigned u = __float_as_uint(f);
    unsigned r = (u + 0x7FFFu + ((u >> 16) & 1u)) >> 16;
    return (short)r;
}

__device__ __forceinline__ bf16x8 pack8(float4 a, float4 b) {
    bf16x8 r;
    r[0] = f2bf(a.x); r[1] = f2bf(a.y); r[2] = f2bf(a.z); r[3] = f2bf(a.w);
    r[4] = f2bf(b.x); r[5] = f2bf(b.y); r[6] = f2bf(b.z); r[7] = f2bf(b.w);
    return r;
}

__device__ __forceinline__ float tanh_fast(float x) {
    float e = __expf(2.f * x);
    return 1.f - 2.f / (e + 1.f);
}

// ---------------- K1: q = tanh(input @ W_dec^T + b_dec); also zero wc accum
__global__ void qproj_kernel(const float* __restrict__ input,
                             const float* __restrict__ W_dec,
                             const float* __restrict__ b_dec,
                             float* __restrict__ q,
                             float* __restrict__ wc) {
    __shared__ float xin[DD];
    const int b = blockIdx.x, d = threadIdx.x;  // 128 threads
    xin[d] = input[b * DD + d];
    wc[b * DD + d] = 0.f;
    __syncthreads();
    const float4* wrow = (const float4*)(W_dec + (size_t)d * DD);
    float acc = 0.f;
#pragma unroll
    for (int k4 = 0; k4 < DD / 4; k4++) {
        float4 w = wrow[k4];
        float4 x = ((const float4*)xin)[k4];
        acc += w.x * x.x + w.y * x.y + w.z * x.z + w.w * x.w;
    }
    q[b * DD + d] = tanh_fast(acc + b_dec[d]);
}

// ---------------- K2: scores[b,s] = sum_d tanh((ctx@W_enc^T)[b,s,d] + b_enc[d]) * q[b,d]
// Per-wave 16-row tiles. ctx A-fragments loaded DIRECTLY global->VGPR (no LDS,
// no per-tile barriers). W_enc staged once in LDS, pre-swizzled into MFMA
// B-fragment order: slot (nt*4+kk)*64+lane holds the lane's 8 bf16 -> lane-linear
// 16B reads, zero bank conflicts.
__global__ __launch_bounds__(256, 4) void score_kernel(
    const float* __restrict__ ctx,
    const float* __restrict__ W_enc,
    const float* __restrict__ b_enc,
    const float* __restrict__ q,
    float* __restrict__ scores) {
    __shared__ short Wl[2048 * 8];  // 32768 B: 8nt x 4kk x 64lane x 8 bf16

    const int t = threadIdx.x;
    // stage + swizzle W_enc (one time per block)
    const float4* W4 = (const float4*)W_enc;
    for (int c = t; c < 2048; c += 256) {   // c = (row, kchunk)
        int row = c >> 4, kc = c & 15;
        float4 f0 = W4[row * 32 + kc * 2];
        float4 f1 = W4[row * 32 + kc * 2 + 1];
        int nt = row >> 4, col = row & 15;
        int kk = kc >> 2, quad = kc & 3;
        int slot = (nt * 4 + kk) * 64 + (col + 16 * quad);
        *(bf16x8*)&Wl[slot * 8] = pack8(f0, f1);
    }

    const int wave = t >> 6, lane = t & 63;
    const int col = lane & 15, quad = lane >> 4;

    float bv[8];
#pragma unroll
    for (int nt = 0; nt < 8; nt++) bv[nt] = b_enc[nt * 16 + col];

    __syncthreads();  // Wl ready; no barriers after this

    const int nwaves = gridDim.x * 4;
    const int wid = blockIdx.x * 4 + wave;
    const int NT = BB * (SS / 16);  // 32768 tiles of 16 rows

    float4 R[8];
    // raw A loader: global row = tile*16 + col; per kk two float4 at quad*8 floats
    auto load_raw = [&](int tile, float4* Rd) {
        const float4* src = (const float4*)(ctx + (size_t)(tile * 16 + col) * DD);
#pragma unroll
        for (int kk = 0; kk < 4; kk++) {
            Rd[2 * kk]     = src[kk * 8 + quad * 2];
            Rd[2 * kk + 1] = src[kk * 8 + quad * 2 + 1];
        }
    };

    if (wid < NT) {
        load_raw(wid, R);
        for (int tile = wid; tile < NT; tile += nwaves) {
            // consume R into bf16 A-frags, then immediately prefetch next tile into R
            bf16x8 a[4];
#pragma unroll
            for (int kk = 0; kk < 4; kk++) a[kk] = pack8(R[2 * kk], R[2 * kk + 1]);
            int nxt = tile + nwaves;
            load_raw(nxt < NT ? nxt : tile, R);

            const int b = tile >> 9;
            float qv[8];
#pragma unroll
            for (int nt = 0; nt < 8; nt++) qv[nt] = q[b * DD + nt * 16 + col];

            f32x4 acc[8];
#pragma unroll
            for (int nt = 0; nt < 8; nt++) {
                f32x4 c = {0.f, 0.f, 0.f, 0.f};
#pragma unroll
                for (int kk = 0; kk < 4; kk++) {
                    bf16x8 bf = *(const bf16x8*)&Wl[((nt * 4 + kk) * 64 + lane) * 8];
                    c = __builtin_amdgcn_mfma_f32_16x16x32_bf16(a[kk], bf, c, 0, 0, 0);
                }
                acc[nt] = c;
            }

#pragma unroll
            for (int r = 0; r < 4; r++) {
                float v = 0.f;
#pragma unroll
                for (int nt = 0; nt < 8; nt++)
                    v += tanh_fast(acc[nt][r] + bv[nt]) * qv[nt];
                v += __shfl_xor(v, 1);
                v += __shfl_xor(v, 2);
                v += __shfl_xor(v, 4);
                v += __shfl_xor(v, 8);
                if (col == 0)
                    scores[(size_t)tile * 16 + quad * 4 + r] = v;
            }
        }
    }
}

// ---------------- K3: in-place softmax over S per batch row (1 block/batch, 1024 thr)
__global__ __launch_bounds__(1024) void softmax_kernel(float* __restrict__ attn) {
    __shared__ float redm[16];
    __shared__ float reds[16];
    const int b = blockIdx.x, t = threadIdx.x;
    float4* row4 = (float4*)(attn + (size_t)b * SS);
    float4 v0 = row4[t];
    float4 v1 = row4[t + 1024];
    float m = fmaxf(fmaxf(fmaxf(v0.x, v0.y), fmaxf(v0.z, v0.w)),
                    fmaxf(fmaxf(v1.x, v1.y), fmaxf(v1.z, v1.w)));
#pragma unroll
    for (int off = 32; off; off >>= 1) m = fmaxf(m, __shfl_xor(m, off));
    if ((t & 63) == 0) redm[t >> 6] = m;
    __syncthreads();
    float M = redm[0];
#pragma unroll
    for (int i = 1; i < 16; i++) M = fmaxf(M, redm[i]);

    float4 e0, e1;
    e0.x = __expf(v0.x - M); e0.y = __expf(v0.y - M);
    e0.z = __expf(v0.z - M); e0.w = __expf(v0.w - M);
    e1.x = __expf(v1.x - M); e1.y = __expf(v1.y - M);
    e1.z = __expf(v1.z - M); e1.w = __expf(v1.w - M);
    float s = e0.x + e0.y + e0.z + e0.w + e1.x + e1.y + e1.z + e1.w;
#pragma unroll
    for (int off = 32; off; off >>= 1) s += __shfl_xor(s, off);
    if ((t & 63) == 0) reds[t >> 6] = s;
    __syncthreads();
    float T = 0.f;
#pragma unroll
    for (int i = 0; i < 16; i++) T += reds[i];
    float inv = 1.f / T;
    e0.x *= inv; e0.y *= inv; e0.z *= inv; e0.w *= inv;
    e1.x *= inv; e1.y *= inv; e1.z *= inv; e1.w *= inv;
    row4[t] = e0;
    row4[t + 1024] = e1;
}

// ---------------- K4: wc[b,d] += sum_s attn[b,s]*ctx[b,s,d] (chunked, atomics)
#define CH 256
__global__ __launch_bounds__(256) void wsum_kernel(const float* __restrict__ ctx,
                                                   const float* __restrict__ attn,
                                                   float* __restrict__ wc) {
    const int t = threadIdx.x;
    const int b = blockIdx.x >> 5;      // 32 chunks per batch
    const int chunk = blockIdx.x & 31;
    const int c4 = t & 31;              // float4 column (covers 128 floats)
    const int rg = t >> 5;              // row group 0..7
    const float4* ctx4 = (const float4*)(ctx + ((size_t)b * SS + (size_t)chunk * CH) * DD);
    const float* arow = attn + (size_t)b * SS + (size_t)chunk * CH;
    float4 acc = {0.f, 0.f, 0.f, 0.f};
#pragma unroll 4
    for (int s = rg; s < CH; s += 8) {
        float a = arow[s];
        float4 v = ctx4[(size_t)s * 32 + c4];
        acc.x += a * v.x;
        acc.y += a * v.y;
        acc.z += a * v.z;
        acc.w += a * v.w;
    }
    __shared__ float4 part[256];
    part[t] = acc;
    __syncthreads();
    if (t < 32) {
        float4 r = part[t];
#pragma unroll
        for (int g = 1; g < 8; g++) {
            float4 p = part[t + g * 32];
            r.x += p.x; r.y += p.y; r.z += p.z; r.w += p.w;
        }
        atomicAdd(&wc[b * DD + 4 * c4 + 0], r.x);
        atomicAdd(&wc[b * DD + 4 * c4 + 1], r.y);
        atomicAdd(&wc[b * DD + 4 * c4 + 2], r.z);
        atomicAdd(&wc[b * DD + 4 * c4 + 3], r.w);
    }
}

// ---------------- K5: h = tanh(concat(wc, q) @ W_out^T)
__global__ void out_kernel(const float* __restrict__ wc,
                           const float* __restrict__ q,
                           const float* __restrict__ W_out,
                           float* __restrict__ h) {
    __shared__ float cat[2 * DD];
    const int b = blockIdx.x, d = threadIdx.x;  // 128 threads
    cat[d] = wc[b * DD + d];
    cat[DD + d] = q[b * DD + d];
    __syncthreads();
    const float4* wrow = (const float4*)(W_out + (size_t)d * 2 * DD);
    float acc = 0.f;
#pragma unroll
    for (int k4 = 0; k4 < 2 * DD / 4; k4++) {
        float4 w = wrow[k4];
        float4 x = ((const float4*)cat)[k4];
        acc += w.x * x.x + w.y * x.y + w.z * x.z + w.w * x.w;
    }
    h[b * DD + d] = tanh_fast(acc);
}

extern "C" void kernel_launch(void* const* d_in, const int* in_sizes, int n_in,
                              void* d_out, int out_size, void* d_ws, size_t ws_size,
                              hipStream_t stream) {
    const float* input = (const float*)d_in[0];
    const float* ctx   = (const float*)d_in[1];
    const float* W_enc = (const float*)d_in[2];
    const float* b_enc = (const float*)d_in[3];
    const float* W_dec = (const float*)d_in[4];
    const float* b_dec = (const float*)d_in[5];
    const float* W_out = (const float*)d_in[6];

    float* h    = (float*)d_out;            // [B, D]
    float* attn = (float*)d_out + BB * DD;  // [B, S] (scores in-place -> softmax)
    float* q    = (float*)d_ws;             // [B, D]
    float* wc   = (float*)d_ws + BB * DD;   // [B, D] accumulators (zeroed in K1)

    qproj_kernel<<<BB, DD, 0, stream>>>(input, W_dec, b_dec, q, wc);
    score_kernel<<<1024, 256, 0, stream>>>(ctx, W_enc, b_enc, q, attn);
    softmax_kernel<<<BB, 1024, 0, stream>>>(attn);
    wsum_kernel<<<BB * 32, 256, 0, stream>>>(ctx, attn, wc);
    out_kernel<<<BB, DD, 0, stream>>>(wc, q, W_out, h);
}